// Round 6
// baseline (2539.546 us; speedup 1.0000x reference)
//
#include <hip/hip_runtime.h>
#include <hip/hip_bf16.h>
#include <stdint.h>

#define BB 128
#define NN 512
#define FF 63
#define HH 128
#define KIN 64     // F+1
#define KTOT 320   // KIN + 2H
#define C5H 640    // 5*H
#define MM 2
#define TPB 640

// ws layout:
//   [0, 819200)            : Wp  - bf16-pair packed gate weights, [m][kk][col] dwords (m*160*640)
//   [1MB, 1MB+33.5MB)      : h_hist fp32 [b][t][j]
//   [1MB+33.5MB, +33.5MB)  : c_hist fp32 [b][t][j]
#define WP_DWORDS (MM * 160 * C5H)
#define HOFF ((size_t)1 << 20)
#define HSZ  ((size_t)BB * NN * HH * 4)

__device__ __forceinline__ uint32_t f2bf_rne(float f) {
    uint32_t u = __float_as_uint(f);
    return (u + 0x7fffu + ((u >> 16) & 1u)) >> 16;
}

__global__ void pack_w_kernel(const float* __restrict__ Wg, uint32_t* __restrict__ Wp) {
    int i = blockIdx.x * blockDim.x + threadIdx.x;
    if (i >= WP_DWORDS) return;
    int col = i % C5H;
    int kk  = (i / C5H) % 160;
    int m   = i / (160 * C5H);
    float w0 = Wg[((size_t)m * KTOT + 2 * kk    ) * C5H + col];
    float w1 = Wg[((size_t)m * KTOT + 2 * kk + 1) * C5H + col];
    Wp[i] = f2bf_rne(w0) | (f2bf_rne(w1) << 16);
}

__device__ __forceinline__ float seg_accum(float acc, const uint32_t* __restrict__ wb,
                                           int wkk0, int n, const float* __restrict__ cf) {
    wb += (size_t)wkk0 * C5H;
#pragma unroll 4
    for (int kk = 0; kk < n; ++kk) {
        uint32_t w = wb[(size_t)kk * C5H];
        acc = fmaf(__uint_as_float(w << 16),         cf[2 * kk],     acc);
        acc = fmaf(__uint_as_float(w & 0xffff0000u), cf[2 * kk + 1], acc);
    }
    return acc;
}

__device__ __forceinline__ float sigm_f(float x) { return 1.0f / (1.0f + __expf(-x)); }
__device__ __forceinline__ float tanh_f(float x) { return 1.0f - 2.0f / (__expf(2.0f * x) + 1.0f); }

__global__ __launch_bounds__(TPB, 1) void tree_lstm_kernel(
    const float* __restrict__ feat,   // (B,N,F)
    const float* __restrict__ treat,  // (B,)
    const float* __restrict__ bgate,  // (M,5H)
    const float* __restrict__ wout,   // (M,H,1)
    const float* __restrict__ bout,   // (M,1)
    const int*   __restrict__ modidx, // (B,N)
    const int*   __restrict__ lchild, // (N,)
    const int*   __restrict__ rchild, // (N,)
    const uint32_t* __restrict__ Wp,  // packed bf16 pairs
    float* __restrict__ hh,           // ws h history
    float* __restrict__ cc,           // ws c history
    float* __restrict__ out)          // (B,N)
{
    __shared__ float combf[KTOT];
    __shared__ float gatesf[C5H];
    __shared__ float partial[HH];
    __shared__ float bg_l[MM * C5H];
    __shared__ float wo_l[MM * HH];
    __shared__ float bo_l[MM];

    const int tid = threadIdx.x;
    const int b   = blockIdx.x;

    for (int i = tid; i < MM * C5H; i += TPB) bg_l[i] = bgate[i];
    for (int i = tid; i < MM * HH;  i += TPB) wo_l[i] = wout[i];
    if (tid < MM) bo_l[tid] = bout[tid];
    const float trt = treat[b];

    float* __restrict__ hb = hh + (size_t)b * NN * HH;
    float* __restrict__ cb = cc + (size_t)b * NN * HH;
    __syncthreads();

    for (int t = 0; t < NN; ++t) {
        const int m  = modidx[b * NN + t];
        const int lc = lchild[t];
        const int rc = rchild[t];
        const int nl = (lc >= 0) ? HH : 0;
        const int nr = (rc >= 0) ? HH : 0;
        const int Kact = KIN + nl + nr;

        // ---- stage compact combined vector [x | lh? | rh?] into LDS ----
        if (tid < Kact) {
            float v;
            if (tid < FF)            v = feat[((size_t)b * NN + t) * FF + tid];
            else if (tid == FF)      v = trt;
            else if (tid < KIN + nl) v = hb[(size_t)lc * HH + (tid - KIN)];
            else                     v = hb[(size_t)rc * HH + (tid - KIN - nl)];
            combf[tid] = v;
        }
        __syncthreads();

        // ---- gates: one column per thread, fp32 acc, bf16 W from L2 ----
        {
            float acc = bg_l[m * C5H + tid];
            const uint32_t* wb = Wp + (size_t)m * (160 * C5H) + tid;
            acc = seg_accum(acc, wb, 0, 32, combf);            // x part (k 0..63)
            int cofs = 64;
            if (nl) { acc = seg_accum(acc, wb, 32, 64, combf + cofs); cofs += 128; }
            if (nr) { acc = seg_accum(acc, wb, 96, 64, combf + cofs); }
            gatesf[tid] = acc;
        }
        __syncthreads();

        // ---- activation, state write, output partials ----
        if (tid < HH) {
            const int j = tid;
            float ig  = gatesf[j];
            float flg = gatesf[HH + j];
            float frg = gatesf[2 * HH + j];
            float og  = gatesf[3 * HH + j];
            float chg = gatesf[4 * HH + j];
            float lcell = nl ? cb[(size_t)lc * HH + j] : 0.0f;
            float rcell = nr ? cb[(size_t)rc * HH + j] : 0.0f;
            float cell = sigm_f(ig) * tanh_f(chg) + sigm_f(flg) * lcell + sigm_f(frg) * rcell;
            float hid  = sigm_f(og) * tanh_f(cell);
            hb[(size_t)t * HH + j] = hid;
            cb[(size_t)t * HH + j] = cell;
            partial[j] = hid * wo_l[m * HH + j];
        }
        __syncthreads();

        // ---- 128-wide reduce by wave 0 ----
        if (tid < 64) {
            float s = partial[tid] + partial[tid + 64];
            #pragma unroll
            for (int off = 32; off; off >>= 1) s += __shfl_down(s, off, 64);
            if (tid == 0) out[(size_t)b * NN + t] = s + bo_l[m];
        }
        __syncthreads();
    }
}

extern "C" void kernel_launch(void* const* d_in, const int* in_sizes, int n_in,
                              void* d_out, int out_size, void* d_ws, size_t ws_size,
                              hipStream_t stream) {
    const float* feat   = (const float*)d_in[0];
    const float* treat  = (const float*)d_in[1];
    const float* Wg     = (const float*)d_in[2];
    const float* bgate  = (const float*)d_in[3];
    const float* wout   = (const float*)d_in[4];
    const float* bout   = (const float*)d_in[5];
    const int*   modidx = (const int*)d_in[6];
    const int*   lchild = (const int*)d_in[7];
    const int*   rchild = (const int*)d_in[8];

    uint32_t* Wp = (uint32_t*)d_ws;
    float* hh = (float*)((char*)d_ws + HOFF);
    float* cc = (float*)((char*)d_ws + HOFF + HSZ);
    float* out = (float*)d_out;

    pack_w_kernel<<<(WP_DWORDS + 255) / 256, 256, 0, stream>>>(Wg, Wp);
    tree_lstm_kernel<<<BB, TPB, 0, stream>>>(feat, treat, bgate, wout, bout,
                                             modidx, lchild, rchild, Wp, hh, cc, out);
}

// Round 7
// 1405.943 us; speedup vs baseline: 1.8063x; 1.8063x over previous
//
#include <hip/hip_runtime.h>
#include <stdint.h>

#define BB 128
#define NN 512
#define FF 63
#define HH 128
#define KTOT 320   // 64 + 2*128
#define C5H 640    // 5*H
#define MM 2
#define TPB 640
#define KK4 40     // KTOT/2/4 : dword-quads per column
#define WP_DW_PER_M (KK4 * C5H * 4)
#define WP_DWORDS (MM * WP_DW_PER_M)
#define HOFF ((size_t)1 << 20)

// ---------------- helpers ----------------
__device__ __forceinline__ uint32_t f2bf_rne(float f) {
    uint32_t u = __float_as_uint(f);
    return (u + 0x7fffu + ((u >> 16) & 1u)) >> 16;
}
__device__ __forceinline__ float sigm_f(float x) { return 1.0f / (1.0f + __expf(-x)); }
__device__ __forceinline__ float tanh_f(float x) { return 1.0f - 2.0f / (__expf(2.0f * x) + 1.0f); }

// W repack: dword d (within module) = kk4*2560 + col*4 + p ; holds bf16 rows (2kk, 2kk+1), kk=4*kk4+p.
// Per-lane dwordx4 = one column's kk-quad; wave (64 consecutive cols) reads 1KB contiguous.
__global__ void pack_w_kernel(const float* __restrict__ Wg, uint32_t* __restrict__ Wp) {
    int i = blockIdx.x * blockDim.x + threadIdx.x;
    if (i >= WP_DWORDS) return;
    int m   = i / WP_DW_PER_M;
    int d   = i % WP_DW_PER_M;
    int p   = d & 3;
    int col = (d >> 2) % C5H;
    int kk4 = d / (C5H * 4);
    int kk  = kk4 * 4 + p;
    float w0 = Wg[((size_t)m * KTOT + 2 * kk    ) * C5H + col];
    float w1 = Wg[((size_t)m * KTOT + 2 * kk + 1) * C5H + col];
    Wp[i] = f2bf_rne(w0) | (f2bf_rne(w1) << 16);
}

#define DOT2(acc, w, x) asm("v_dot2_f32_bf16 %0, %1, %2, %0" : "+v"(acc) : "v"(w), "v"(x))

// raw barriers: lgkm-only for LDS phases (keeps prefetch loads in flight);
// vmcnt+lgkm at end-of-step (makes the c-store visible to next step's prefetch).
#define BAR_L()  do { asm volatile("s_waitcnt lgkmcnt(0)" ::: "memory"); \
                      __builtin_amdgcn_s_barrier(); \
                      asm volatile("" ::: "memory"); } while (0)
#define BAR_VL() do { asm volatile("s_waitcnt vmcnt(0) lgkmcnt(0)" ::: "memory"); \
                      __builtin_amdgcn_s_barrier(); \
                      asm volatile("" ::: "memory"); } while (0)

__device__ __forceinline__ float seg_dot(float acc, const uint4* __restrict__ w4,
                                         int g0, int ng, const uint32_t* __restrict__ cf) {
#pragma unroll 4
    for (int g = 0; g < ng; ++g) {
        uint4 w = w4[(size_t)(g0 + g) * C5H];          // coalesced 16B/lane
        uint4 x = *(const uint4*)(cf + 4 * g);         // LDS b128 broadcast (all lanes same addr)
        DOT2(acc, w.x, x.x);
        DOT2(acc, w.y, x.y);
        DOT2(acc, w.z, x.z);
        DOT2(acc, w.w, x.w);
    }
    return acc;
}

__global__ __launch_bounds__(TPB, 1) void tree_lstm_kernel(
    const float* __restrict__ feat,   // (B,N,F)
    const float* __restrict__ treat,  // (B,)
    const float* __restrict__ bgate,  // (M,5H)
    const float* __restrict__ wout,   // (M,H,1)
    const float* __restrict__ bout,   // (M,1)
    const int*   __restrict__ modidx, // (B,N)
    const int*   __restrict__ lchild, // (N,)
    const int*   __restrict__ rchild, // (N,)
    const uint32_t* __restrict__ Wp,  // packed bf16 pairs, [m][kk4][col][4]
    float* __restrict__ cc,           // ws c history f32 [b][t][j]
    float* __restrict__ out)          // (B,N)
{
    __shared__ __align__(16) ushort   h_lds[NN * HH];   // 128 KB bf16 h history
    __shared__ __align__(16) uint32_t comb_x[32];       // packed bf16 x-part (64 vals)
    __shared__ float gatesf[C5H];
    __shared__ float partial[HH];
    __shared__ float bg_l[MM * C5H];
    __shared__ float wo_l[MM * HH];
    __shared__ float bo_l[MM];
    __shared__ int   mod_l[NN], lc_l[NN], rc_l[NN];

    const int tid = threadIdx.x;
    const int b   = blockIdx.x;
    const float trt = treat[b];
    float* __restrict__ cb = cc + (size_t)b * NN * HH;

    for (int i = tid; i < MM * C5H; i += TPB) bg_l[i] = bgate[i];
    for (int i = tid; i < MM * HH;  i += TPB) wo_l[i] = wout[i];
    if (tid < MM) bo_l[tid] = bout[tid];
    for (int i = tid; i < NN; i += TPB) {
        mod_l[i] = modidx[b * NN + i];
        lc_l[i]  = lchild[i];
        rc_l[i]  = rchild[i];
    }
    // prefetch feats for t=0
    float fx0 = 0.f, fx1 = 0.f;
    if (tid < 32) {
        fx0 = feat[(size_t)b * NN * FF + 2 * tid];
        if (tid < 31) fx1 = feat[(size_t)b * NN * FF + 2 * tid + 1];
    }
    BAR_L();

    for (int t = 0; t < NN; ++t) {
        const int m  = mod_l[t];
        const int lc = lc_l[t];
        const int rc = rc_l[t];

        // ---- Phase A: pack x (from prefetched regs), issue next-step feat +
        //      child-cell prefetches. Loads stay in flight across BAR_L. ----
        if (tid < 32) {
            comb_x[tid] = f2bf_rne(fx0) | (f2bf_rne((tid == 31) ? trt : fx1) << 16);
            if (t + 1 < NN) {
                fx0 = feat[((size_t)b * NN + t + 1) * FF + 2 * tid];
                if (tid < 31) fx1 = feat[((size_t)b * NN + t + 1) * FF + 2 * tid + 1];
            }
        }
        float pcl = 0.f, pcr = 0.f;
        if (tid < HH) {
            if (lc >= 0) pcl = cb[(size_t)lc * HH + tid];   // consumed in Phase C
            if (rc >= 0) pcr = cb[(size_t)rc * HH + tid];
        }
        BAR_L();

        // ---- Phase B: gate dot-products, one column per thread ----
        {
            float acc = bg_l[m * C5H + tid];
            const uint4* w4 = (const uint4*)Wp + (size_t)m * (KK4 * C5H) + tid;
            acc = seg_dot(acc, w4, 0, 8, comb_x);                                    // x   (kk4 0..7)
            if (lc >= 0) acc = seg_dot(acc, w4,  8, 16, (const uint32_t*)&h_lds[lc * HH]); // lh (8..23)
            if (rc >= 0) acc = seg_dot(acc, w4, 24, 16, (const uint32_t*)&h_lds[rc * HH]); // rh (24..39)
            gatesf[tid] = acc;
        }
        BAR_L();

        // ---- Phase C: activation, state writes, output partials ----
        if (tid < HH) {
            float ig  = gatesf[tid];
            float flg = gatesf[HH + tid];
            float frg = gatesf[2 * HH + tid];
            float og  = gatesf[3 * HH + tid];
            float chg = gatesf[4 * HH + tid];
            float cell = sigm_f(ig) * tanh_f(chg) + sigm_f(flg) * pcl + sigm_f(frg) * pcr;
            float hid  = sigm_f(og) * tanh_f(cell);
            cb[(size_t)t * HH + tid] = cell;                       // f32 (accumulating path)
            h_lds[t * HH + tid] = (ushort)f2bf_rne(hid);           // bf16 h history
            partial[tid] = hid * wo_l[m * HH + tid];
        }
        BAR_VL();   // drain c-store so next step's prefetch can't read stale

        // ---- Phase D: wave 0 reduces output; other waves proceed to next A ----
        if (tid < 64) {
            float s = partial[tid] + partial[tid + 64];
#pragma unroll
            for (int off = 32; off; off >>= 1) s += __shfl_down(s, off, 64);
            if (tid == 0) out[(size_t)b * NN + t] = s + bo_l[m];
        }
    }
}

extern "C" void kernel_launch(void* const* d_in, const int* in_sizes, int n_in,
                              void* d_out, int out_size, void* d_ws, size_t ws_size,
                              hipStream_t stream) {
    const float* feat   = (const float*)d_in[0];
    const float* treat  = (const float*)d_in[1];
    const float* Wg     = (const float*)d_in[2];
    const float* bgate  = (const float*)d_in[3];
    const float* wout   = (const float*)d_in[4];
    const float* bout   = (const float*)d_in[5];
    const int*   modidx = (const int*)d_in[6];
    const int*   lchild = (const int*)d_in[7];
    const int*   rchild = (const int*)d_in[8];

    uint32_t* Wp = (uint32_t*)d_ws;
    float* cc  = (float*)((char*)d_ws + HOFF);
    float* out = (float*)d_out;

    pack_w_kernel<<<(WP_DWORDS + 255) / 256, 256, 0, stream>>>(Wg, Wp);
    tree_lstm_kernel<<<BB, TPB, 0, stream>>>(feat, treat, bgate, wout, bout,
                                             modidx, lchild, rchild, Wp, cc, out);
}